// Round 3
// baseline (292.897 us; speedup 1.0000x reference)
//
#include <hip/hip_runtime.h>
#include <math.h>

typedef __bf16 bf16x8 __attribute__((ext_vector_type(8)));
typedef float f32x16 __attribute__((ext_vector_type(16)));

#define NTOK 131072
#define HDIM 128
#define ODIM 128
#define NEXP 8
// K padded to 9 kt-steps of 16: kt 0..7 = real H, kt 8 = bias row (x side = 1.0)

__device__ __forceinline__ unsigned short f2bf(float f){
  union { float f; unsigned u; } v; v.f = f;
  unsigned r = v.u + 0x7FFFu + ((v.u >> 16) & 1u);
  return (unsigned short)(r >> 16);
}

// ---------------------------------------------------------------------------
// Kernel 1: pack W into A-operand fragment layout (transposed GEMM: A[m=o][k=h])
// pw flat: [e][mt(4)][kt(9)][lane(64)][j(8)] bf16
// A-frag mapping (v_mfma_f32_32x32x16_bf16): A[m=lane&31][k=(lane>>5)*8+j]
// kt==8: k-local 0 row = b_expert[e][o], rest zero.
__global__ void pack_w(const float* __restrict__ we, const float* __restrict__ be,
                       unsigned short* __restrict__ pw){
  int f = blockIdx.x * 256 + threadIdx.x;      // 0..18431, one per (e,mt,kt,l)
  int l  = f & 63;
  int kt = (f >> 6) % 9;
  int emt = f / (64 * 9);
  int mt = emt & 3;
  int e  = emt >> 2;
  int o  = (mt << 5) + (l & 31);
  unsigned short vals[8];
#pragma unroll
  for (int j = 0; j < 8; ++j){
    int kl = ((l >> 5) << 3) + j;              // k within 16-step
    float v;
    if (kt < 8){
      int h = kt * 16 + kl;
      v = we[(e * HDIM + h) * ODIM + o];
    } else {
      v = (kl == 0) ? be[e * ODIM + o] : 0.0f;
    }
    vals[j] = f2bf(v);
  }
  *(bf16x8*)(pw + (size_t)f * 8) = *(bf16x8*)vals;
}

// ---------------------------------------------------------------------------
// Kernel 2: FUSED gating + MoE FFN. 128 tokens/block, 256 threads.
// Phase A (gating): thread t owns token t>>1, half (t&1) of its row.
//   f32 logit partials vs LDS w_gate, __shfl_xor(1) combine, even lane does
//   top-2 + softmax (f32 — precision-critical), writes glds. Same regs then
//   converted to bf16 B-frags in LDS. x is read exactly once per block.
// Phase B (FFN): transposed MFMA C[o][token]; gate lane-uniform (token=lane&31).
//   aw STREAMED from L2 (no aw[9] array — this caused the R1/R2 spill of tot:
//   618 MB of scratch writes). Peak regs ~200 < 256.
// Epilogue: LDS transpose -> coalesced out stores.
__launch_bounds__(256, 2)
__global__ void moe_fused(const float* __restrict__ x, const float* __restrict__ wg,
                          const unsigned short* __restrict__ pw, float* __restrict__ out){
  __shared__ unsigned short xlds[4 * 9 * 64 * 8];   // 36 KiB (later reused: f32 transpose)
  __shared__ float glds[128 * 8];                   //  4 KiB
  __shared__ float wgl[128 * 8];                    //  4 KiB

  int t = threadIdx.x;
  size_t tokbase = (size_t)blockIdx.x * 128;

  // stage w_gate (flat copy, [h][e] f32)
  ((float4*)wgl)[t] = ((const float4*)wg)[t];

  // bias x-column (kt=8): B[k=0][*]=1.0
  {
    int btg = t >> 6, bl = t & 63;
    unsigned long long* dst = (unsigned long long*)&xlds[(((btg * 9) + 8) * 64 + bl) * 8];
    dst[0] = (bl < 32) ? 0x3F80ull : 0ull;
    dst[1] = 0ull;
  }

  // --- Phase A: read half-row f32, gating in f32 ---
  int tok = t >> 1, hf = t & 1;
  const float4* xr = (const float4*)(x + (tokbase + tok) * HDIM) + hf * 16;
  float4 xv[16];
#pragma unroll
  for (int i = 0; i < 16; ++i) xv[i] = xr[i];

  __syncthreads();   // wgl ready

  float lg[8];
#pragma unroll
  for (int e = 0; e < 8; ++e) lg[e] = 0.0f;
#pragma unroll
  for (int i = 0; i < 16; ++i){
    const float* wr = wgl + (hf * 64 + i * 4) * 8;
#pragma unroll
    for (int e = 0; e < 8; ++e)
      lg[e] += xv[i].x * wr[e] + xv[i].y * wr[8 + e] +
               xv[i].z * wr[16 + e] + xv[i].w * wr[24 + e];
  }
#pragma unroll
  for (int e = 0; e < 8; ++e) lg[e] += __shfl_xor(lg[e], 1);

  if ((t & 1) == 0){
    // top-2, ties -> lowest index (matches lax.top_k)
    int i1 = 0; float v1 = lg[0];
#pragma unroll
    for (int e = 1; e < 8; ++e) if (lg[e] > v1){ v1 = lg[e]; i1 = e; }
    int i2 = -1; float v2 = -3.4e38f;
#pragma unroll
    for (int e = 0; e < 8; ++e) if (e != i1 && lg[e] > v2){ v2 = lg[e]; i2 = e; }
    float ex = __expf(v2 - v1);
    float inv = 1.0f / (1.0f + ex);
    float og[8];
#pragma unroll
    for (int e = 0; e < 8; ++e) og[e] = 0.0f;
    og[i1] = inv; og[i2] = ex * inv;
    float4* gp = (float4*)(glds + tok * 8);
    gp[0] = make_float4(og[0], og[1], og[2], og[3]);
    gp[1] = make_float4(og[4], og[5], og[6], og[7]);
  }

  // convert held f32 regs -> bf16 B-frags in LDS
  // B-frag: B[k=(lane>>5)*8+j][n=lane&31] = x[token=tg*32+(lane&31)][h=kt*16+k]
  {
    int tg = tok >> 5;
#pragma unroll
    for (int i = 0; i < 16; ++i){
      int h0 = hf * 64 + i * 4;
      int kt = h0 >> 4, kk = h0 & 15;
      int l = (tok & 31) + ((kk >> 3) << 5);
      int j0 = kk & 7;
      unsigned long long pk = (unsigned long long)f2bf(xv[i].x)
                            | ((unsigned long long)f2bf(xv[i].y) << 16)
                            | ((unsigned long long)f2bf(xv[i].z) << 32)
                            | ((unsigned long long)f2bf(xv[i].w) << 48);
      *(unsigned long long*)&xlds[((((tg * 9) + kt) * 64 + l) * 8) + j0] = pk;
    }
  }
  __syncthreads();

  // --- Phase B: MFMA ---
  int w = t >> 6, l = t & 63;
  int l32 = l & 31, lh = l >> 5;
  int mtb = (w & 1) * 2;          // o-tile base
  int tgb = (w >> 1) * 2;         // token-group base

  // x B-frags for this wave's 2 token-groups (72 VGPRs, e-invariant, loaded once)
  bf16x8 xb[2][9];
#pragma unroll
  for (int ti = 0; ti < 2; ++ti)
#pragma unroll
    for (int kt = 0; kt < 9; ++kt)
      xb[ti][kt] = *(const bf16x8*)&xlds[((((tgb + ti) * 9) + kt) * 64 + l) * 8];

  f32x16 zero16;
#pragma unroll
  for (int i = 0; i < 16; ++i) zero16[i] = 0.0f;
  f32x16 tot[2][2];
#pragma unroll
  for (int mi = 0; mi < 2; ++mi)
#pragma unroll
    for (int ti = 0; ti < 2; ++ti) tot[mi][ti] = zero16;

  const bf16x8* pwp = (const bf16x8*)pw;
#pragma unroll 1
  for (int e = 0; e < 8; ++e){
    // gate scalars from LDS (2 regs, not 16)
    float g0 = glds[((tgb + 0) * 32 + l32) * 8 + e];
    float g1 = glds[((tgb + 1) * 32 + l32) * 8 + e];
#pragma unroll 1
    for (int mi = 0; mi < 2; ++mi){
      const bf16x8* ap = pwp + ((size_t)(e * 4 + mtb + mi) * 9) * 64 + l;
      f32x16 p0 = zero16, p1 = zero16;
#pragma unroll
      for (int kt = 0; kt < 9; ++kt){
        bf16x8 a = ap[kt * 64];                       // streamed from L2, no array
        p0 = __builtin_amdgcn_mfma_f32_32x32x16_bf16(a, xb[0][kt], p0, 0, 0, 0);
        p1 = __builtin_amdgcn_mfma_f32_32x32x16_bf16(a, xb[1][kt], p1, 0, 0, 0);
      }
#pragma unroll
      for (int r = 0; r < 16; ++r){
        tot[mi][0][r] += g0 * p0[r];
        tot[mi][1][r] += g1 * p1[r];
      }
    }
  }

  // --- Epilogue: LDS transpose -> coalesced stores ---
  float* tb = (float*)xlds;
  int myphase = w >> 1;                 // waves 0,1 own tokens 0..63; 2,3 own 64..127
#pragma unroll 1
  for (int ph = 0; ph < 2; ++ph){
    __syncthreads();
    if (myphase == ph){
#pragma unroll
      for (int mi = 0; mi < 2; ++mi){
        int mt = mtb + mi;
#pragma unroll
        for (int ti = 0; ti < 2; ++ti){
          int trow = ti * 32 + l32;     // 0..63
#pragma unroll
          for (int rg = 0; rg < 4; ++rg){
            int o = mt * 32 + rg * 8 + lh * 4;
            int cs = (o >> 2) ^ l32;    // swizzled f4 chunk
            float4 st = make_float4(tot[mi][ti][rg * 4 + 0], tot[mi][ti][rg * 4 + 1],
                                    tot[mi][ti][rg * 4 + 2], tot[mi][ti][rg * 4 + 3]);
            *(float4*)&tb[trow * 128 + cs * 4] = st;
          }
        }
      }
    }
    __syncthreads();
#pragma unroll
    for (int i = 0; i < 8; ++i){
      int idx = i * 256 + t;            // f4 id, 0..2047
      int trow = idx >> 5, c = idx & 31;
      int cs = c ^ (trow & 31);
      float4 v = *(float4*)&tb[trow * 128 + cs * 4];
      *(float4*)(out + (tokbase + (size_t)ph * 64 + trow) * ODIM + c * 4) = v;
    }
  }
}

// ---------------------------------------------------------------------------
extern "C" void kernel_launch(void* const* d_in, const int* in_sizes, int n_in,
                              void* d_out, int out_size, void* d_ws, size_t ws_size,
                              hipStream_t stream){
  const float* x  = (const float*)d_in[0];
  const float* wg = (const float*)d_in[1];
  // d_in[2] = w_noise (inactive in eval mode)
  const float* we = (const float*)d_in[3];
  const float* be = (const float*)d_in[4];
  // d_in[5] = top_k (== 2, baked in)
  float* out = (float*)d_out;

  unsigned short* pw = (unsigned short*)d_ws;              // 294,912 B

  pack_w   <<<72,   256, 0, stream>>>(we, be, pw);
  moe_fused<<<1024, 256, 0, stream>>>(x, wg, pw, out);
}

// Round 4
// 161.316 us; speedup vs baseline: 1.8157x; 1.8157x over previous
//
#include <hip/hip_runtime.h>
#include <math.h>

typedef __bf16 bf16x8 __attribute__((ext_vector_type(8)));
typedef float f32x16 __attribute__((ext_vector_type(16)));

#define NTOK 131072
#define HDIM 128
#define ODIM 128
#define NEXP 8
// K padded to 9 kt-steps of 16: kt 0..7 = real H, kt 8 = bias row (x side = 1.0)

__device__ __forceinline__ unsigned short f2bf(float f){
  union { float f; unsigned u; } v; v.f = f;
  unsigned r = v.u + 0x7FFFu + ((v.u >> 16) & 1u);
  return (unsigned short)(r >> 16);
}

// ---------------------------------------------------------------------------
// Kernel 1: pack W into A-operand fragment layout (transposed GEMM: A[m=o][k=h])
// pw flat: [e][mt(4)][kt(9)][lane(64)][j(8)] bf16
// A-frag (v_mfma_f32_32x32x16_bf16): A[m=lane&31][k=(lane>>5)*8+j]
// kt==8: k-local 0 row = b_expert[e][o], rest zero.
__global__ void pack_w(const float* __restrict__ we, const float* __restrict__ be,
                       unsigned short* __restrict__ pw){
  int f = blockIdx.x * 256 + threadIdx.x;      // 0..18431
  int l  = f & 63;
  int kt = (f >> 6) % 9;
  int emt = f / (64 * 9);
  int mt = emt & 3;
  int e  = emt >> 2;
  int o  = (mt << 5) + (l & 31);
  unsigned short vals[8];
#pragma unroll
  for (int j = 0; j < 8; ++j){
    int kl = ((l >> 5) << 3) + j;
    float v;
    if (kt < 8){
      int h = kt * 16 + kl;
      v = we[(e * HDIM + h) * ODIM + o];
    } else {
      v = (kl == 0) ? be[e * ODIM + o] : 0.0f;
    }
    vals[j] = f2bf(v);
  }
  *(bf16x8*)(pw + (size_t)f * 8) = *(bf16x8*)vals;
}

// ---------------------------------------------------------------------------
// Kernel 2: FUSED gating + MoE FFN. 64 tokens/block, 256 threads (4 waves).
// LDS 39 KiB: xs f32 (33 KiB; later overlaid by bf16 frags (18 KiB), then by
// f32 transpose buf (32 KiB)) + wgl 4 KiB + glds 2 KiB ([e][token], conflict-free).
// Wave w owns o-tile w (32 o's); both token-groups share each streamed a-frag.
// CRITICAL (R1-R3 lesson): accumulators are NAMED vars (tot0/tot1), every loop
// touching register arrays fully unrolled — dynamic indexing put tot in scratch
// (537 MB/launch of spill writes = the entire mystery WRITE_SIZE).
__launch_bounds__(256, 2)
__global__ void moe_fused(const float* __restrict__ x, const float* __restrict__ wg,
                          const unsigned short* __restrict__ pw, float* __restrict__ out){
  __shared__ char lds[33792 + 4096 + 2048];
  float* xs            = (float*)lds;                 // [tok(64)][132] f32
  unsigned short* frag = (unsigned short*)lds;        // overlay: [tg2][kt9][l64][j8]
  float* tb            = (float*)lds;                 // overlay: [trow64][128] f32
  float* wgl           = (float*)(lds + 33792);       // [h128][e8] f32
  float* glds          = (float*)(lds + 33792 + 4096);// [e8][tok64] f32

  int t = threadIdx.x;
  size_t tokbase = (size_t)blockIdx.x * 64;

  // --- stage w_gate + x tile (fully coalesced: 2 KB contiguous per wave-instr)
  ((float4*)wgl)[t] = ((const float4*)wg)[t];
  {
    const float4* xsrc = (const float4*)(x + tokbase * HDIM);
#pragma unroll
    for (int i = 0; i < 8; ++i){
      int idx = i * 256 + t;
      int tok = idx >> 5, c = idx & 31;
      *(float4*)&xs[tok * 132 + c * 4] = xsrc[idx];
    }
  }
  __syncthreads();

  // --- gating (wave 0; w_gate reads broadcast across lanes) + conversion reads
  float4 cv[8];
#pragma unroll
  for (int i = 0; i < 8; ++i)
    cv[i] = *(float4*)&xs[(t >> 2) * 132 + (t & 3) * 32 + i * 4];

  if (t < 64){
    float lg[8];
#pragma unroll
    for (int e = 0; e < 8; ++e) lg[e] = 0.0f;
#pragma unroll 8
    for (int c = 0; c < 32; ++c){
      float4 v = *(float4*)&xs[t * 132 + c * 4];
      const float* wr = wgl + c * 32;
#pragma unroll
      for (int e = 0; e < 8; ++e)
        lg[e] += v.x * wr[e] + v.y * wr[8 + e] + v.z * wr[16 + e] + v.w * wr[24 + e];
    }
    // top-2, ties -> lowest index (matches lax.top_k)
    int i1 = 0; float v1 = lg[0];
#pragma unroll
    for (int e = 1; e < 8; ++e) if (lg[e] > v1){ v1 = lg[e]; i1 = e; }
    int i2 = -1; float v2 = -3.4e38f;
#pragma unroll
    for (int e = 0; e < 8; ++e) if (e != i1 && lg[e] > v2){ v2 = lg[e]; i2 = e; }
    float ex = __expf(v2 - v1);
    float inv = 1.0f / (1.0f + ex);
#pragma unroll
    for (int e = 0; e < 8; ++e)
      glds[e * 64 + t] = (e == i1) ? inv : ((e == i2) ? ex * inv : 0.0f);
  }
  __syncthreads();   // all xs reads done -> frag overlay safe

  // --- convert f32 regs -> bf16 B-frags (overlaid on xs)
  // B-frag: B[k=(lane>>5)*8+j][n=lane&31] = x[token=tg*32+(lane&31)][h=kt*16+k]
  {
    int tokL = t >> 2, q = t & 3, tg = tokL >> 5;
#pragma unroll
    for (int jb = 0; jb < 4; ++jb){
      int h0 = q * 32 + jb * 8;
      int kt = h0 >> 4;
      int lslot = (tokL & 31) + 32 * ((h0 >> 3) & 1);
      float4 a = cv[2 * jb], b = cv[2 * jb + 1];
      unsigned long long lo = (unsigned long long)f2bf(a.x)
                            | ((unsigned long long)f2bf(a.y) << 16)
                            | ((unsigned long long)f2bf(a.z) << 32)
                            | ((unsigned long long)f2bf(a.w) << 48);
      unsigned long long hi = (unsigned long long)f2bf(b.x)
                            | ((unsigned long long)f2bf(b.y) << 16)
                            | ((unsigned long long)f2bf(b.z) << 32)
                            | ((unsigned long long)f2bf(b.w) << 48);
      unsigned long long* dst =
        (unsigned long long*)&frag[(((tg * 9) + kt) * 64 + lslot) * 8];
      dst[0] = lo; dst[1] = hi;
    }
    // bias kt=8 slots: 128 slots (2 tg x 64 l)
    if (t < 128){
      int btg = t >> 6, bl = t & 63;
      unsigned long long* dst =
        (unsigned long long*)&frag[(((btg * 9) + 8) * 64 + bl) * 8];
      dst[0] = (bl < 32) ? 0x3F80ull : 0ull;   // bf16 1.0 at j==0, k<8 half
      dst[1] = 0ull;
    }
  }
  __syncthreads();   // frags ready

  // --- Phase B: MFMA. C[o][token] = sum_h W[h][o] * x[token][h]
  int w = t >> 6, l = t & 63, l32 = l & 31, lh = l >> 5;

  bf16x8 xb0[9], xb1[9];
#pragma unroll
  for (int kt = 0; kt < 9; ++kt){
    xb0[kt] = *(const bf16x8*)&frag[((0 * 9 + kt) * 64 + l) * 8];
    xb1[kt] = *(const bf16x8*)&frag[((1 * 9 + kt) * 64 + l) * 8];
  }
  __syncthreads();   // frag reads done -> tb overlay safe (tb written after e-loop)

  f32x16 zero16;
#pragma unroll
  for (int i = 0; i < 16; ++i) zero16[i] = 0.0f;
  f32x16 tot0 = zero16, tot1 = zero16;

  const bf16x8* pwp = (const bf16x8*)pw;
#pragma unroll 1
  for (int e = 0; e < 8; ++e){
    float g0 = glds[e * 64 + l32];
    float g1 = glds[e * 64 + 32 + l32];
    const bf16x8* ap = pwp + ((size_t)(e * 4 + w) * 9) * 64 + l;
    f32x16 p0 = zero16, p1 = zero16;
#pragma unroll
    for (int kt = 0; kt < 9; ++kt){
      bf16x8 a = ap[kt * 64];                 // 1 KB/wave contiguous L2 stream
      p0 = __builtin_amdgcn_mfma_f32_32x32x16_bf16(a, xb0[kt], p0, 0, 0, 0);
      p1 = __builtin_amdgcn_mfma_f32_32x32x16_bf16(a, xb1[kt], p1, 0, 0, 0);
    }
#pragma unroll
    for (int r = 0; r < 16; ++r){             // static indices only
      tot0[r] += g0 * p0[r];
      tot1[r] += g1 * p1[r];
    }
  }

  // --- epilogue: LDS transpose (XOR swizzle) -> coalesced stores
  // C/D map: token(col)=l32, o(row)=w*32 + rg*8 + lh*4 + rr
  {
#pragma unroll
    for (int rg = 0; rg < 4; ++rg){
      int o = w * 32 + rg * 8 + lh * 4;
      {
        int trow = 0 * 32 + l32;
        int cs = (o >> 2) ^ l32;
        *(float4*)&tb[trow * 128 + cs * 4] =
          make_float4(tot0[rg * 4 + 0], tot0[rg * 4 + 1], tot0[rg * 4 + 2], tot0[rg * 4 + 3]);
      }
      {
        int trow = 1 * 32 + l32;
        int cs = (o >> 2) ^ l32;
        *(float4*)&tb[trow * 128 + cs * 4] =
          make_float4(tot1[rg * 4 + 0], tot1[rg * 4 + 1], tot1[rg * 4 + 2], tot1[rg * 4 + 3]);
      }
    }
  }
  __syncthreads();
#pragma unroll
  for (int i = 0; i < 8; ++i){
    int idx = i * 256 + t;
    int trow = idx >> 5, c = idx & 31;
    int cs = c ^ (trow & 31);
    float4 v = *(float4*)&tb[trow * 128 + cs * 4];
    *(float4*)(out + (tokbase + trow) * ODIM + c * 4) = v;
  }
}

// ---------------------------------------------------------------------------
extern "C" void kernel_launch(void* const* d_in, const int* in_sizes, int n_in,
                              void* d_out, int out_size, void* d_ws, size_t ws_size,
                              hipStream_t stream){
  const float* x  = (const float*)d_in[0];
  const float* wg = (const float*)d_in[1];
  // d_in[2] = w_noise (inactive in eval mode)
  const float* we = (const float*)d_in[3];
  const float* be = (const float*)d_in[4];
  // d_in[5] = top_k (== 2, baked in)
  float* out = (float*)d_out;

  unsigned short* pw = (unsigned short*)d_ws;          // 294,912 B

  pack_w   <<<72,   256, 0, stream>>>(we, be, pw);
  moe_fused<<<2048, 256, 0, stream>>>(x, wg, pw, out);
}